// Round 13
// baseline (520.194 us; speedup 1.0000x reference)
//
#include <hip/hip_runtime.h>
#include <hip/hip_cooperative_groups.h>
#include <hip/hip_bf16.h>

#define B_ 4
#define N_ 20000
#define D_ 128
#define E_ 100000
#define NT_ 1250            // 16-node tiles
#define GRID_ 768
#define NWAVES_ (GRID_ * 4)
#define NJOBS_ (B_ * NT_)   // 5000
#define NBK_ 8
#define GRB_ 50             // fallback greduce blocks

namespace cg = cooperative_groups;

typedef __attribute__((ext_vector_type(8))) short bf16x8;
typedef __attribute__((ext_vector_type(4))) float f32x4;

// ws layout (float units) — shared by both paths unless noted:
// [0] flag(int)  [4] cnt(unsigned)  [8,12) qg
// [64,4160)      gbuf[NBK_][512]          (cooperative g buckets)
// [4224,4480)    w5f (float2[128])
// [4608,12800)   w7f (2048 x bf16x8, 32 KB)
// [12800,92800)  qi (B x N)
// [92800,172800) qj (B x N)
// [180000,180512) g (fallback)
// [185000,825000) gpart[1250][512] (fallback)

// ======================= cooperative single kernel =======================
__global__ __launch_bounds__(256, 4) void k_fused(
    const float* __restrict__ emb, const float* __restrict__ W7,
    const float* __restrict__ W6, const float* __restrict__ w5,
    const float* __restrict__ wno, const int* __restrict__ edges,
    int* flag, unsigned* cnt, float* qg, float* gbuf,
    float2* w5f, bf16x8* w7f, float* qi, float* qj, float* out)
{
    __shared__ bf16x8 sB[2048];
    __shared__ float  sgf[512];
    __shared__ float4 srw[4];
    __shared__ int    lastf;

    cg::grid_group gg = cg::this_grid();
    const int bx = blockIdx.x, t = threadIdx.x;
    const int wv = t >> 6, lane = t & 63, rc = lane & 15, kg = lane >> 4;

    // ---------- phase 0: pack w7f, flag, w5f, zero buckets ----------
    if (bx < 8) {
        int f = bx * 256 + t;
        int ftt = f >> 8, fs = (f >> 6) & 3, ln = f & 63;
        int fkg = ln >> 4, frc = ln & 15;
        int col = ftt * 16 + frc, k0 = fs * 32 + fkg * 8;
        union { bf16x8 v; __hip_bfloat16 h[8]; } pk;
        #pragma unroll
        for (int m = 0; m < 8; ++m)
            pk.h[m] = __float2bfloat16(W7[(k0 + m) * D_ + col]);
        w7f[f] = pk.v;
    } else if (bx == 8) {
        #pragma unroll
        for (int i = 0; i < 16; ++i) gbuf[t + 256 * i] = 0.f;
        if (t < 128) w5f[t] = make_float2(w5[D_ + t], w5[2 * D_ + t]);
        if (t == 0) *cnt = 0u;
        if (t < 64) {
            unsigned v = ((const unsigned*)edges)[2 * t + 1];
            unsigned long long any = __ballot(v != 0u);
            if (t == 0) *flag = (any == 0ULL) ? 1 : 0;
        }
    }
    if (t == 0) lastf = 0;
    __threadfence();
    gg.sync();

    // ---------- stage sB (once per block) ----------
    {
        const uint4* src = (const uint4*)w7f;
        uint4* dst = (uint4*)sB;
        #pragma unroll
        for (int i = 0; i < 8; ++i) dst[t + 256 * i] = src[t + 256 * i];
    }
    float2 wij[8];
    #pragma unroll
    for (int tt = 0; tt < 8; ++tt) wij[tt] = w5f[tt * 16 + rc];
    __syncthreads();

    // ---------- phase A: (tile,b) jobs, R5 wave body ----------
    const int gw = bx * 4 + wv;
    for (int j = gw; j < NJOBS_; j += NWAVES_) {
        const int b = j / NT_, tile = j - b * NT_;

        const float4* p = (const float4*)(emb + (size_t)b * N_ * D_)
                          + ((size_t)(tile * 16 + rc)) * 32 + kg * 2;
        float4 a[8];
        #pragma unroll
        for (int s = 0; s < 4; ++s) { a[2*s] = p[s*8]; a[2*s+1] = p[s*8+1]; }

        bf16x8 pk[4];
        #pragma unroll
        for (int s = 0; s < 4; ++s) {
            union { bf16x8 v; __hip_bfloat16 h[8]; } u;
            float4 x = a[2*s], y = a[2*s+1];
            u.h[0] = __float2bfloat16(x.x); u.h[1] = __float2bfloat16(x.y);
            u.h[2] = __float2bfloat16(x.z); u.h[3] = __float2bfloat16(x.w);
            u.h[4] = __float2bfloat16(y.x); u.h[5] = __float2bfloat16(y.y);
            u.h[6] = __float2bfloat16(y.z); u.h[7] = __float2bfloat16(y.w);
            pk[s] = u.v;
        }

        // g partials: reduce over 16 rc-lanes, bucketed atomics
        #pragma unroll
        for (int m = 1; m < 16; m <<= 1) {
            #pragma unroll
            for (int i = 0; i < 8; ++i) {
                a[i].x += __shfl_xor(a[i].x, m);
                a[i].y += __shfl_xor(a[i].y, m);
                a[i].z += __shfl_xor(a[i].z, m);
                a[i].w += __shfl_xor(a[i].w, m);
            }
        }
        if (rc == 0) {
            float* gp = gbuf + (bx & (NBK_ - 1)) * 512 + b * 128;
            #pragma unroll
            for (int s = 0; s < 4; ++s) {
                int c0 = s * 32 + kg * 8;
                atomicAdd(&gp[c0 + 0], a[2*s].x);
                atomicAdd(&gp[c0 + 1], a[2*s].y);
                atomicAdd(&gp[c0 + 2], a[2*s].z);
                atomicAdd(&gp[c0 + 3], a[2*s].w);
                atomicAdd(&gp[c0 + 4], a[2*s+1].x);
                atomicAdd(&gp[c0 + 5], a[2*s+1].y);
                atomicAdd(&gp[c0 + 6], a[2*s+1].z);
                atomicAdd(&gp[c0 + 7], a[2*s+1].w);
            }
        }

        f32x4 acc[8] = {};
        #pragma unroll
        for (int s = 0; s < 4; ++s)
            #pragma unroll
            for (int tt = 0; tt < 8; ++tt)
                acc[tt] = __builtin_amdgcn_mfma_f32_16x16x32_bf16(pk[s], sB[tt * 256 + s * 64 + lane], acc[tt], 0, 0, 0);

        float qip[4] = {0,0,0,0}, qjp[4] = {0,0,0,0};
        #pragma unroll
        for (int tt = 0; tt < 8; ++tt) {
            #pragma unroll
            for (int r = 0; r < 4; ++r) {
                float pv = acc[tt][r];
                float lr = (pv >= 0.f) ? pv : 0.01f * pv;
                qip[r] += lr * wij[tt].x;
                qjp[r] += lr * wij[tt].y;
            }
        }
        #pragma unroll
        for (int m = 1; m < 16; m <<= 1) {
            #pragma unroll
            for (int r = 0; r < 4; ++r) {
                qip[r] += __shfl_xor(qip[r], m);
                qjp[r] += __shfl_xor(qjp[r], m);
            }
        }
        if (rc == 0) {
            #pragma unroll
            for (int r = 0; r < 4; ++r) {
                int node = tile * 16 + kg * 4 + r;
                qi[b * N_ + node] = qip[r];
                qj[b * N_ + node] = qjp[r];
            }
        }
    }

    // ---------- last block computes qg + noop ----------
    __threadfence();
    __syncthreads();
    if (t == 0) {
        unsigned old = atomicAdd(cnt, 1u);
        if (old == GRID_ - 1) lastf = 1;
    }
    __syncthreads();
    if (lastf) {
        float s0 = 0.f, s1 = 0.f;
        #pragma unroll
        for (int k = 0; k < NBK_; ++k) {
            s0 += gbuf[k * 512 + t];
            s1 += gbuf[k * 512 + t + 256];
        }
        sgf[t] = s0; sgf[t + 256] = s1;
        __syncthreads();
        const int col = t & 127, h = t >> 7;
        float p0 = 0.f, p1 = 0.f;
        #pragma unroll 8
        for (int d = 0; d < 128; ++d) {
            float w6 = W6[d * D_ + col];
            p0 += sgf[h * 128 + d] * w6;
            p1 += sgf[(h + 2) * 128 + d] * w6;
        }
        float l0 = (p0 >= 0.f) ? p0 : 0.01f * p0;
        float l1 = (p1 >= 0.f) ? p1 : 0.01f * p1;
        float w5g = w5[col], wn = wno[col];
        float vq0 = l0 * w5g, vq1 = l1 * w5g;
        float vn0 = sgf[h * 128 + col] * wn, vn1 = sgf[(h + 2) * 128 + col] * wn;
        #pragma unroll
        for (int m = 1; m < 64; m <<= 1) {
            vq0 += __shfl_xor(vq0, m);
            vq1 += __shfl_xor(vq1, m);
            vn0 += __shfl_xor(vn0, m);
            vn1 += __shfl_xor(vn1, m);
        }
        if (lane == 0) srw[wv] = make_float4(vq0, vq1, vn0, vn1);
        __syncthreads();
        if (t == 0) {
            float4 a0 = srw[0], a1 = srw[1], a2 = srw[2], a3 = srw[3];
            qg[0] = a0.x + a1.x;
            qg[2] = a0.y + a1.y;
            qg[1] = a2.x + a3.x;
            qg[3] = a2.y + a3.y;
            out[0 * (size_t)(E_ + 1) + E_] = a0.z + a1.z;
            out[2 * (size_t)(E_ + 1) + E_] = a0.w + a1.w;
            out[1 * (size_t)(E_ + 1) + E_] = a2.z + a3.z;
            out[3 * (size_t)(E_ + 1) + E_] = a2.w + a3.w;
        }
    }
    __threadfence();
    gg.sync();

    // ---------- phase D: edge gather ----------
    const int e = bx * 256 + t;
    if (e < E_) {
        int u, v;
        if (*flag) { int4 w = ((const int4*)edges)[e]; u = w.x; v = w.z; }
        else       { int2 w = ((const int2*)edges)[e]; u = w.x; v = w.y; }
        float q0 = qg[0], q1 = qg[1], q2 = qg[2], q3 = qg[3];
        out[0 * (size_t)(E_ + 1) + e] = q0 + qi[0 * N_ + u] + qj[0 * N_ + v];
        out[1 * (size_t)(E_ + 1) + e] = q1 + qi[1 * N_ + u] + qj[1 * N_ + v];
        out[2 * (size_t)(E_ + 1) + e] = q2 + qi[2 * N_ + u] + qj[2 * N_ + v];
        out[3 * (size_t)(E_ + 1) + e] = q3 + qi[3 * N_ + u] + qj[3 * N_ + v];
    }
}

// ======================= fallback: proven R5 pipeline =======================
__global__ __launch_bounds__(256) void k_prep(
    const float* __restrict__ W7, const float* __restrict__ w5,
    const unsigned* __restrict__ ew, int* __restrict__ flag,
    unsigned* __restrict__ cnt, float* __restrict__ g,
    float2* __restrict__ w5f, bf16x8* __restrict__ w7f)
{
    const int bx = blockIdx.x, t = threadIdx.x;
    if (bx == 8) {
        g[t] = 0.f; g[t + 256] = 0.f;
        if (t < 128) w5f[t] = make_float2(w5[D_ + t], w5[2 * D_ + t]);
        if (t == 0) *cnt = 0u;
        if (t < 64) {
            unsigned v = ew[2 * t + 1];
            unsigned long long any = __ballot(v != 0u);
            if (t == 0) *flag = (any == 0ULL) ? 1 : 0;
        }
        return;
    }
    int f = bx * 256 + t;
    int tt = f >> 8, s = (f >> 6) & 3, lane = f & 63;
    int kg = lane >> 4, rc = lane & 15;
    int col = tt * 16 + rc, k0 = s * 32 + kg * 8;
    union { bf16x8 v; __hip_bfloat16 h[8]; } pk;
    #pragma unroll
    for (int m = 0; m < 8; ++m)
        pk.h[m] = __float2bfloat16(W7[(k0 + m) * D_ + col]);
    w7f[f] = pk.v;
}

__global__ __launch_bounds__(256) void k_main(
    const float* __restrict__ emb, const bf16x8* __restrict__ w7f,
    const float2* __restrict__ w5f, float* __restrict__ gpart,
    float* __restrict__ qi, float* __restrict__ qj)
{
    __shared__ bf16x8 sB[2048];
    const int t = threadIdx.x, b = blockIdx.y;
    const int wv = t >> 6, lane = t & 63, rc = lane & 15, kg = lane >> 4;
    const int tile = blockIdx.x * 4 + wv;
    const int tc = (tile < NT_) ? tile : (NT_ - 1);

    const float4* p = (const float4*)(emb + (size_t)b * N_ * D_)
                      + ((size_t)(tc * 16 + rc)) * 32 + kg * 2;
    float4 a[8];
    #pragma unroll
    for (int s = 0; s < 4; ++s) { a[2*s] = p[s*8]; a[2*s+1] = p[s*8+1]; }
    {
        const uint4* src = (const uint4*)w7f;
        uint4* dst = (uint4*)sB;
        #pragma unroll
        for (int i = 0; i < 8; ++i) dst[t + 256 * i] = src[t + 256 * i];
    }
    float2 wij[8];
    #pragma unroll
    for (int tt = 0; tt < 8; ++tt) wij[tt] = w5f[tt * 16 + rc];
    __syncthreads();

    bf16x8 pk[4];
    #pragma unroll
    for (int s = 0; s < 4; ++s) {
        union { bf16x8 v; __hip_bfloat16 h[8]; } u;
        float4 x = a[2*s], y = a[2*s+1];
        u.h[0] = __float2bfloat16(x.x); u.h[1] = __float2bfloat16(x.y);
        u.h[2] = __float2bfloat16(x.z); u.h[3] = __float2bfloat16(x.w);
        u.h[4] = __float2bfloat16(y.x); u.h[5] = __float2bfloat16(y.y);
        u.h[6] = __float2bfloat16(y.z); u.h[7] = __float2bfloat16(y.w);
        pk[s] = u.v;
    }
    #pragma unroll
    for (int m = 1; m < 16; m <<= 1) {
        #pragma unroll
        for (int i = 0; i < 8; ++i) {
            a[i].x += __shfl_xor(a[i].x, m);
            a[i].y += __shfl_xor(a[i].y, m);
            a[i].z += __shfl_xor(a[i].z, m);
            a[i].w += __shfl_xor(a[i].w, m);
        }
    }
    if (tile < NT_ && rc == 0) {
        float* gp = gpart + (size_t)tile * 512 + b * 128;
        #pragma unroll
        for (int s = 0; s < 4; ++s) {
            int c0 = s * 32 + kg * 8;
            *reinterpret_cast<float4*>(gp + c0)     = a[2*s];
            *reinterpret_cast<float4*>(gp + c0 + 4) = a[2*s+1];
        }
    }
    f32x4 acc[8] = {};
    #pragma unroll
    for (int s = 0; s < 4; ++s)
        #pragma unroll
        for (int tt = 0; tt < 8; ++tt)
            acc[tt] = __builtin_amdgcn_mfma_f32_16x16x32_bf16(pk[s], sB[tt * 256 + s * 64 + lane], acc[tt], 0, 0, 0);

    float qip[4] = {0,0,0,0}, qjp[4] = {0,0,0,0};
    #pragma unroll
    for (int tt = 0; tt < 8; ++tt) {
        #pragma unroll
        for (int r = 0; r < 4; ++r) {
            float pv = acc[tt][r];
            float lr = (pv >= 0.f) ? pv : 0.01f * pv;
            qip[r] += lr * wij[tt].x;
            qjp[r] += lr * wij[tt].y;
        }
    }
    #pragma unroll
    for (int m = 1; m < 16; m <<= 1) {
        #pragma unroll
        for (int r = 0; r < 4; ++r) {
            qip[r] += __shfl_xor(qip[r], m);
            qjp[r] += __shfl_xor(qjp[r], m);
        }
    }
    if (tile < NT_ && rc == 0) {
        #pragma unroll
        for (int r = 0; r < 4; ++r) {
            int node = tile * 16 + kg * 4 + r;
            qi[b * N_ + node] = qip[r];
            qj[b * N_ + node] = qjp[r];
        }
    }
}

__global__ __launch_bounds__(512) void k_greduce(
    const float* __restrict__ gpart, float* __restrict__ g,
    unsigned* __restrict__ cnt, const float* __restrict__ W6,
    const float* __restrict__ w5, const float* __restrict__ wno,
    float* __restrict__ qg, float* __restrict__ out)
{
    __shared__ float sp[4][B_][D_];
    __shared__ float sr[2][B_], srn[2][B_];
    __shared__ int lastf;
    const int t = threadIdx.x;
    {
        const int c0 = blockIdx.x * 25;
        float s = 0.f;
        #pragma unroll 5
        for (int i = 0; i < 25; ++i)
            s += gpart[(size_t)(c0 + i) * 512 + t];
        atomicAdd(&g[t], s);
    }
    __threadfence();
    __syncthreads();
    if (t == 0) {
        unsigned old = atomicAdd(cnt, 1u);
        lastf = (old == GRB_ - 1) ? 1 : 0;
    }
    __syncthreads();
    if (!lastf) return;
    __threadfence();
    const int col = t & 127, q = t >> 7;
    {
        float p[B_] = {0, 0, 0, 0};
        for (int d = q * 32; d < q * 32 + 32; ++d) {
            float w6 = W6[d * D_ + col];
            #pragma unroll
            for (int b = 0; b < B_; ++b) p[b] += g[b * D_ + d] * w6;
        }
        #pragma unroll
        for (int b = 0; b < B_; ++b) sp[q][b][col] = p[b];
    }
    __syncthreads();
    if (t < 128) {
        float vq[B_], vn[B_];
        #pragma unroll
        for (int b = 0; b < B_; ++b) {
            float pp = sp[0][b][t] + sp[1][b][t] + sp[2][b][t] + sp[3][b][t];
            float lr = (pp >= 0.f) ? pp : 0.01f * pp;
            vq[b] = lr * w5[t];
            vn[b] = g[b * D_ + t] * wno[t];
        }
        #pragma unroll
        for (int m = 1; m < 64; m <<= 1) {
            #pragma unroll
            for (int b = 0; b < B_; ++b) {
                vq[b] += __shfl_xor(vq[b], m);
                vn[b] += __shfl_xor(vn[b], m);
            }
        }
        if ((t & 63) == 0) {
            #pragma unroll
            for (int b = 0; b < B_; ++b) { sr[t >> 6][b] = vq[b]; srn[t >> 6][b] = vn[b]; }
        }
    }
    __syncthreads();
    if (t == 0) {
        #pragma unroll
        for (int b = 0; b < B_; ++b) {
            qg[b] = sr[0][b] + sr[1][b];
            out[(size_t)b * (E_ + 1) + E_] = srn[0][b] + srn[1][b];
        }
    }
}

__global__ __launch_bounds__(256) void k_edge(
    const int* __restrict__ edges, const int* __restrict__ flag,
    const float* __restrict__ qg, const float* __restrict__ qi,
    const float* __restrict__ qj, float* __restrict__ out)
{
    int e = blockIdx.x * 256 + threadIdx.x;
    if (e >= E_) return;
    int u, v;
    if (*flag) { int4 w = ((const int4*)edges)[e]; u = w.x; v = w.z; }
    else       { int2 w = ((const int2*)edges)[e]; u = w.x; v = w.y; }
    float q0 = qg[0], q1 = qg[1], q2 = qg[2], q3 = qg[3];
    out[0 * (size_t)(E_ + 1) + e] = q0 + qi[0 * N_ + u] + qj[0 * N_ + v];
    out[1 * (size_t)(E_ + 1) + e] = q1 + qi[1 * N_ + u] + qj[1 * N_ + v];
    out[2 * (size_t)(E_ + 1) + e] = q2 + qi[2 * N_ + u] + qj[2 * N_ + v];
    out[3 * (size_t)(E_ + 1) + e] = q3 + qi[3 * N_ + u] + qj[3 * N_ + v];
}

extern "C" void kernel_launch(void* const* d_in, const int* in_sizes, int n_in,
                              void* d_out, int out_size, void* d_ws, size_t ws_size,
                              hipStream_t stream)
{
    const float* emb   = (const float*)d_in[0];
    const int*   edges = (const int*)d_in[1];
    const float* W6    = (const float*)d_in[2];
    const float* W7    = (const float*)d_in[3];
    const float* w5    = (const float*)d_in[4];
    const float* wno   = (const float*)d_in[5];
    float* out = (float*)d_out;

    float* W = (float*)d_ws;
    int*      flag  = (int*)W;
    unsigned* cnt   = (unsigned*)(W + 4);
    float*    qg    = W + 8;
    float*    gbuf  = W + 64;
    float2*   w5f   = (float2*)(W + 4224);
    bf16x8*   w7f   = (bf16x8*)(W + 4608);
    float*    qi    = W + 12800;
    float*    qj    = W + 92800;
    float*    gfb   = W + 180000;     // fallback g
    float*    gpart = W + 185000;     // fallback gpart

    void* args[] = {
        (void*)&emb, (void*)&W7, (void*)&W6, (void*)&w5, (void*)&wno,
        (void*)&edges, (void*)&flag, (void*)&cnt, (void*)&qg, (void*)&gbuf,
        (void*)&w5f, (void*)&w7f, (void*)&qi, (void*)&qj, (void*)&out
    };
    hipError_t err = hipLaunchCooperativeKernel(
        (const void*)k_fused, dim3(GRID_), dim3(256), args, 0, stream);

    if (err != hipSuccess) {
        (void)hipGetLastError();   // clear error state, use proven pipeline
        hipLaunchKernelGGL(k_prep, dim3(9), dim3(256), 0, stream,
                           W7, w5, (const unsigned*)edges, flag, cnt, gfb, w5f, w7f);
        hipLaunchKernelGGL(k_main, dim3(313, B_), dim3(256), 0, stream,
                           emb, w7f, w5f, gpart, qi, qj);
        hipLaunchKernelGGL(k_greduce, dim3(GRB_), dim3(512), 0, stream,
                           gpart, gfb, cnt, W6, w5, wno, qg, out);
        hipLaunchKernelGGL(k_edge, dim3((E_ + 255) / 256), dim3(256), 0, stream,
                           edges, flag, qg, qi, qj, out);
    }
}